// Round 6
// baseline (135.673 us; speedup 1.0000x reference)
//
#include <hip/hip_runtime.h>

#define NSTREAMS 4
#define DIM 256
#define BM 16
#define NTHREADS 1024
#define TILES 16

typedef __attribute__((ext_vector_type(8))) short short8;
typedef __attribute__((ext_vector_type(4))) float f32x4;

// f32 -> bf16 round-to-nearest-even (scalar, bit-twiddle)
static __device__ __forceinline__ short f2bf(float x) {
    union { float f; unsigned int u; } c; c.f = x;
    unsigned int u = c.u;
    unsigned int lsb = (u >> 16) & 1u;
    u += 0x7fffu + lsb;
    return (short)(u >> 16);
}
// f32x4 -> packed bf16x4 via HW v_cvt_pk_bf16_f32 (RNE, bit-identical to f2bf)
static __device__ __forceinline__ int2 f2bf4(float4 v) {
    unsigned int lo, hi;
    asm("v_cvt_pk_bf16_f32 %0, %1, %2" : "=v"(lo) : "v"(v.x), "v"(v.y));
    asm("v_cvt_pk_bf16_f32 %0, %1, %2" : "=v"(hi) : "v"(v.z), "v"(v.w));
    int2 r; r.x = (int)lo; r.y = (int)hi;
    return r;
}

// Block-uniform float -> SGPR (all lanes hold the same value).
static __device__ __forceinline__ float rfl(float x) {
    int i = __builtin_amdgcn_readfirstlane(__builtin_bit_cast(int, x));
    return __builtin_bit_cast(float, i);
}

// Block barrier that drains LDS ops only — does NOT drain vmcnt, so global
// loads issued before it stay in flight across the barrier (T4 discipline).
static __device__ __forceinline__ void barrier_lgkm() {
    asm volatile("s_waitcnt lgkmcnt(0)\n\ts_barrier" ::: "memory");
}

// Sinkhorn (4x4, 10 iters, tau=0.05) + two softmaxes.
// h_out[0..15]=h_res (row-major s,t), [16..19]=h_pre, [20..23]=h_post
static __device__ void compute_h(const float* __restrict__ hres_l,
                                 const float* __restrict__ hpre_l,
                                 const float* __restrict__ hpost_l,
                                 float* h_out) {
    const float inv_tau = 1.0f / 0.05f;
    float z[4][4];
    for (int i = 0; i < 4; ++i)
        for (int j = 0; j < 4; ++j)
            z[i][j] = hres_l[i * 4 + j] * inv_tau;
    float u[4] = {0.f, 0.f, 0.f, 0.f};
    float v[4] = {0.f, 0.f, 0.f, 0.f};
    const float logm = -logf(4.0f);
    for (int it = 0; it < 10; ++it) {
        for (int i = 0; i < 4; ++i) {
            float m = -1e30f;
            for (int j = 0; j < 4; ++j) m = fmaxf(m, z[i][j] + v[j]);
            float ss = 0.f;
            for (int j = 0; j < 4; ++j) ss += expf(z[i][j] + v[j] - m);
            u[i] = logm - (m + logf(ss));
        }
        for (int j = 0; j < 4; ++j) {
            float m = -1e30f;
            for (int i = 0; i < 4; ++i) m = fmaxf(m, z[i][j] + u[i]);
            float ss = 0.f;
            for (int i = 0; i < 4; ++i) ss += expf(z[i][j] + u[i] - m);
            v[j] = logm - (m + logf(ss));
        }
    }
    for (int i = 0; i < 4; ++i)
        for (int j = 0; j < 4; ++j)
            h_out[i * 4 + j] = expf(z[i][j] + u[i] + v[j]) * 4.0f;
    {
        float m = fmaxf(fmaxf(hpre_l[0], hpre_l[1]), fmaxf(hpre_l[2], hpre_l[3]));
        float e0 = expf(hpre_l[0] - m), e1 = expf(hpre_l[1] - m);
        float e2 = expf(hpre_l[2] - m), e3 = expf(hpre_l[3] - m);
        float ss = e0 + e1 + e2 + e3;
        h_out[16] = e0 / ss; h_out[17] = e1 / ss; h_out[18] = e2 / ss; h_out[19] = e3 / ss;
    }
    {
        float m = fmaxf(fmaxf(hpost_l[0], hpost_l[1]), fmaxf(hpost_l[2], hpost_l[3]));
        float e0 = expf(hpost_l[0] - m), e1 = expf(hpost_l[1] - m);
        float e2 = expf(hpost_l[2] - m), e3 = expf(hpost_l[3] - m);
        float ss = e0 + e1 + e2 + e3;
        h_out[20] = e0 / ss; h_out[21] = e1 / ss; h_out[22] = e2 / ss; h_out[23] = e3 / ss;
    }
}

__global__ void prep_h_kernel(const float* __restrict__ hres_l,
                              const float* __restrict__ hpre_l,
                              const float* __restrict__ hpost_l,
                              float* __restrict__ ws) {
    if (threadIdx.x == 0) compute_h(hres_l, hpre_l, hpost_l, ws);
}

// Convert W to bf16 into ws (RNE) + compute h in block 0 (disjoint ws region).
__global__ __launch_bounds__(256) void prep_wh_kernel(const float* __restrict__ Wb,
                                                      short* __restrict__ wbf,
                                                      const float* __restrict__ hres_l,
                                                      const float* __restrict__ hpre_l,
                                                      const float* __restrict__ hpost_l,
                                                      float* __restrict__ ws_h) {
    int idx = blockIdx.x * 256 + threadIdx.x;   // 16384 float4 tasks
    float4 v = reinterpret_cast<const float4*>(Wb)[idx];
    reinterpret_cast<int2*>(wbf)[idx] = f2bf4(v);
    if (blockIdx.x == 0 && threadIdx.x == 0)
        compute_h(hres_l, hpre_l, hpost_l, ws_h);
}

template <bool USE_WSW>
__global__ __launch_bounds__(NTHREADS, 1) void fused_kernel(
    const float* __restrict__ res,
    const float* __restrict__ Wb,
    const short* __restrict__ wbf,    // bf16 W in ws (when USE_WSW)
    const float* __restrict__ hptr,   // 24 floats in ws, or nullptr
    const float* __restrict__ hres_l,
    const float* __restrict__ hpre_l,
    const float* __restrict__ hpost_l,
    float* __restrict__ out)
{
    // SWAPPED-OPERAND GEMM: compute C^T = W·bi^T. By the proven fragment
    // layouts, the A-fragment (W rows) and B-fragment (bi rows) are the SAME
    // LDS reads as the unswapped version — only the mfma argument order
    // changes. Result: lane (lr,lk) of wave w holds C[batch=lr][d=w*16+lk*4
    // ..+3] directly in acc — no bo_lds round-trip, no mid barrier.
    // bi_lds double-buffered -> exactly ONE barrier per tile.
    __shared__ __align__(16) short W_lds[DIM * DIM];         // 128 KB swizzled
    __shared__ __align__(16) short bi_lds[2][BM][DIM + 8];   // 2 x 8.25 KB
    __shared__ float h_sh[24];

    const int t  = threadIdx.x;
    const int w  = t >> 6;    // wave id 0..15: owns d in [16w, 16w+16)
    const int l  = t & 63;
    const int lr = l & 15;    // batch row owned; also W-row (A) / bi-row (B) lane index
    const int lk = l >> 4;    // k-block 0..3; also d-subblock in the accumulator

    const long tile0 = (long)blockIdx.x * TILES;
    const long tstride = (long)BM * (NSTREAMS * DIM);
    // this thread's residual slice: row lr, streams 0..3, d0 = w*16 + lk*4
    const int d0 = w * 16 + lk * 4;
    const float* rbase = res + (tile0 * BM + lr) * (NSTREAMS * DIM) + d0;

    // ---- prologue: issue tile-0 res loads FIRST (longest latency)
    float4 A0, A1, A2, A3;
    A0 = *reinterpret_cast<const float4*>(rbase + 0 * DIM);
    A1 = *reinterpret_cast<const float4*>(rbase + 1 * DIM);
    A2 = *reinterpret_cast<const float4*>(rbase + 2 * DIM);
    A3 = *reinterpret_cast<const float4*>(rbase + 3 * DIM);

    // ---- stage W into LDS, XOR-swizzled: byte dst = (row<<9)|(koff^((row&7)<<4))
    #pragma unroll
    for (int i = 0; i < 8; ++i) {
        int c = t * 8 + i;            // 16B-chunk id, 0..8191 (8192*16B = 128KB)
        int row = c >> 5;             // W row (= output col d); 512B per row
        int koff = (c & 31) * 16;     // byte offset within row
        int dst = (row << 9) | (koff ^ ((row & 7) << 4));
        int4 wv;
        if (USE_WSW) {
            wv = reinterpret_cast<const int4*>(wbf)[c];
        } else {
            const float4* wp = reinterpret_cast<const float4*>(Wb) + c * 2;
            float4 wa = wp[0], wb2 = wp[1];
            int2 loq = f2bf4(wa), hiq = f2bf4(wb2);
            wv.x = loq.x; wv.y = loq.y; wv.z = hiq.x; wv.w = hiq.y;
        }
        *reinterpret_cast<int4*>(reinterpret_cast<char*>(W_lds) + dst) = wv;
    }

    if (hptr) {
        if (t < 24) h_sh[t] = hptr[t];
    } else if (t == 0) {
        compute_h(hres_l, hpre_l, hpost_l, h_sh);
    }
    barrier_lgkm();

    // h coefficients are block-uniform: pin them to SGPRs.
    const float hp0 = rfl(h_sh[16]), hp1 = rfl(h_sh[17]);
    const float hp2 = rfl(h_sh[18]), hp3 = rfl(h_sh[19]);
    float hres[4][4];
    #pragma unroll
    for (int s = 0; s < 4; ++s)
        #pragma unroll
        for (int tt = 0; tt < 4; ++tt)
            hres[s][tt] = rfl(h_sh[s * 4 + tt]);
    float hq[4] = {rfl(h_sh[20]), rfl(h_sh[21]), rfl(h_sh[22]), rfl(h_sh[23])};

    // ---- issue tile-1 loads into B-set (in flight across tile 0's GEMM)
    float4 B0, B1, B2, B3;
    {
        const float4* p0 = reinterpret_cast<const float4*>(rbase + tstride + 0 * DIM);
        const float4* p1 = reinterpret_cast<const float4*>(rbase + tstride + 1 * DIM);
        const float4* p2 = reinterpret_cast<const float4*>(rbase + tstride + 2 * DIM);
        const float4* p3 = reinterpret_cast<const float4*>(rbase + tstride + 3 * DIM);
        B0 = *p0; B1 = *p1; B2 = *p2; B3 = *p3;
    }

    // ---- stage bi(0) into buf0 + opart(0) from A-set
    float4 opart[4];
    {
        float4 bi;
        bi.x = hp0 * A0.x + hp1 * A1.x + hp2 * A2.x + hp3 * A3.x;
        bi.y = hp0 * A0.y + hp1 * A1.y + hp2 * A2.y + hp3 * A3.y;
        bi.z = hp0 * A0.z + hp1 * A1.z + hp2 * A2.z + hp3 * A3.z;
        bi.w = hp0 * A0.w + hp1 * A1.w + hp2 * A2.w + hp3 * A3.w;
        *reinterpret_cast<int2*>(&bi_lds[0][lr][d0]) = f2bf4(bi);
        #pragma unroll
        for (int tt = 0; tt < 4; ++tt) {
            opart[tt].x = hres[0][tt] * A0.x + hres[1][tt] * A1.x + hres[2][tt] * A2.x + hres[3][tt] * A3.x;
            opart[tt].y = hres[0][tt] * A0.y + hres[1][tt] * A1.y + hres[2][tt] * A2.y + hres[3][tt] * A3.y;
            opart[tt].z = hres[0][tt] * A0.z + hres[1][tt] * A1.z + hres[2][tt] * A2.z + hres[3][tt] * A3.z;
            opart[tt].w = hres[0][tt] * A0.w + hres[1][tt] * A1.w + hres[2][tt] * A2.w + hres[3][tt] * A3.w;
        }
    }
    barrier_lgkm();

    // GEMM addressing (constant over tiles): lane reads W row (w*16 + lr)
    const int dcol = w * 16 + lr;
    const char* wbase = reinterpret_cast<const char*>(W_lds) + (dcol << 9);
    const int dswz = (dcol & 7) << 4;

    for (int ti = 0; ti < TILES; ti += 2) {
        // ======== even half: GEMM from buf0; stage B-set -> buf1 ============
        {
            if (ti + 2 < TILES) {   // issue A-set loads for tile ti+2
                const float* rb = rbase + (ti + 2) * tstride;
                A0 = *reinterpret_cast<const float4*>(rb + 0 * DIM);
                A1 = *reinterpret_cast<const float4*>(rb + 1 * DIM);
                A2 = *reinterpret_cast<const float4*>(rb + 2 * DIM);
                A3 = *reinterpret_cast<const float4*>(rb + 3 * DIM);
            }
            __builtin_amdgcn_sched_barrier(0);
            f32x4 acc = {0.f, 0.f, 0.f, 0.f};
            #pragma unroll
            for (int k0 = 0; k0 < DIM; k0 += 32) {
                short8 bfrag = *reinterpret_cast<const short8*>(&bi_lds[0][lr][k0 + lk * 8]);
                short8 afrag = *reinterpret_cast<const short8*>(
                    wbase + ((k0 * 2 + lk * 16) ^ dswz));
                // swapped: A=W, B=bi -> acc = C[batch=lr][d0..d0+3]
                acc = __builtin_amdgcn_mfma_f32_16x16x32_bf16(afrag, bfrag, acc, 0, 0, 0);
            }
            // ---- epilogue straight from acc (no LDS, no barrier needed)
            {
                float* obase = out + (((tile0 + ti) * BM + lr) * 4) * DIM + d0;
                #pragma unroll
                for (int tt = 0; tt < 4; ++tt) {
                    float4 o;
                    o.x = opart[tt].x + hq[tt] * acc[0];
                    o.y = opart[tt].y + hq[tt] * acc[1];
                    o.z = opart[tt].z + hq[tt] * acc[2];
                    o.w = opart[tt].w + hq[tt] * acc[3];
                    *reinterpret_cast<float4*>(obase + tt * DIM) = o;
                }
            }
            // ---- stage bi(ti+1) -> buf1 + opart(ti+1) from B-set
            {
                float4 bi;
                bi.x = hp0 * B0.x + hp1 * B1.x + hp2 * B2.x + hp3 * B3.x;
                bi.y = hp0 * B0.y + hp1 * B1.y + hp2 * B2.y + hp3 * B3.y;
                bi.z = hp0 * B0.z + hp1 * B1.z + hp2 * B2.z + hp3 * B3.z;
                bi.w = hp0 * B0.w + hp1 * B1.w + hp2 * B2.w + hp3 * B3.w;
                *reinterpret_cast<int2*>(&bi_lds[1][lr][d0]) = f2bf4(bi);
                #pragma unroll
                for (int tt = 0; tt < 4; ++tt) {
                    opart[tt].x = hres[0][tt] * B0.x + hres[1][tt] * B1.x + hres[2][tt] * B2.x + hres[3][tt] * B3.x;
                    opart[tt].y = hres[0][tt] * B0.y + hres[1][tt] * B1.y + hres[2][tt] * B2.y + hres[3][tt] * B3.y;
                    opart[tt].z = hres[0][tt] * B0.z + hres[1][tt] * B1.z + hres[2][tt] * B2.z + hres[3][tt] * B3.z;
                    opart[tt].w = hres[0][tt] * B0.w + hres[1][tt] * B1.w + hres[2][tt] * B2.w + hres[3][tt] * B3.w;
                }
            }
            barrier_lgkm();   // buf1 visible; buf0 reads drained (safe to rewrite next half)
        }
        // ======== odd half: GEMM from buf1; stage A-set -> buf0 =============
        {
            if (ti + 3 < TILES) {   // issue B-set loads for tile ti+3
                const float* rb = rbase + (ti + 3) * tstride;
                B0 = *reinterpret_cast<const float4*>(rb + 0 * DIM);
                B1 = *reinterpret_cast<const float4*>(rb + 1 * DIM);
                B2 = *reinterpret_cast<const float4*>(rb + 2 * DIM);
                B3 = *reinterpret_cast<const float4*>(rb + 3 * DIM);
            }
            __builtin_amdgcn_sched_barrier(0);
            f32x4 acc = {0.f, 0.f, 0.f, 0.f};
            #pragma unroll
            for (int k0 = 0; k0 < DIM; k0 += 32) {
                short8 bfrag = *reinterpret_cast<const short8*>(&bi_lds[1][lr][k0 + lk * 8]);
                short8 afrag = *reinterpret_cast<const short8*>(
                    wbase + ((k0 * 2 + lk * 16) ^ dswz));
                acc = __builtin_amdgcn_mfma_f32_16x16x32_bf16(afrag, bfrag, acc, 0, 0, 0);
            }
            {
                float* obase = out + (((tile0 + ti + 1) * BM + lr) * 4) * DIM + d0;
                #pragma unroll
                for (int tt = 0; tt < 4; ++tt) {
                    float4 o;
                    o.x = opart[tt].x + hq[tt] * acc[0];
                    o.y = opart[tt].y + hq[tt] * acc[1];
                    o.z = opart[tt].z + hq[tt] * acc[2];
                    o.w = opart[tt].w + hq[tt] * acc[3];
                    *reinterpret_cast<float4*>(obase + tt * DIM) = o;
                }
            }
            if (ti + 2 < TILES) {   // stage bi(ti+2) -> buf0 + opart(ti+2) from A-set
                float4 bi;
                bi.x = hp0 * A0.x + hp1 * A1.x + hp2 * A2.x + hp3 * A3.x;
                bi.y = hp0 * A0.y + hp1 * A1.y + hp2 * A2.y + hp3 * A3.y;
                bi.z = hp0 * A0.z + hp1 * A1.z + hp2 * A2.z + hp3 * A3.z;
                bi.w = hp0 * A0.w + hp1 * A1.w + hp2 * A2.w + hp3 * A3.w;
                *reinterpret_cast<int2*>(&bi_lds[0][lr][d0]) = f2bf4(bi);
                #pragma unroll
                for (int tt = 0; tt < 4; ++tt) {
                    opart[tt].x = hres[0][tt] * A0.x + hres[1][tt] * A1.x + hres[2][tt] * A2.x + hres[3][tt] * A3.x;
                    opart[tt].y = hres[0][tt] * A0.y + hres[1][tt] * A1.y + hres[2][tt] * A2.y + hres[3][tt] * A3.y;
                    opart[tt].z = hres[0][tt] * A0.z + hres[1][tt] * A1.z + hres[2][tt] * A2.z + hres[3][tt] * A3.z;
                    opart[tt].w = hres[0][tt] * A0.w + hres[1][tt] * A1.w + hres[2][tt] * A2.w + hres[3][tt] * A3.w;
                }
            }
            barrier_lgkm();   // buf0 visible; buf1 reads drained
        }
    }
}

extern "C" void kernel_launch(void* const* d_in, const int* in_sizes, int n_in,
                              void* d_out, int out_size, void* d_ws, size_t ws_size,
                              hipStream_t stream) {
    const float* res     = (const float*)d_in[0];
    const float* hres_l  = (const float*)d_in[1];
    const float* hpre_l  = (const float*)d_in[2];
    const float* hpost_l = (const float*)d_in[3];
    const float* Wb      = (const float*)d_in[4];
    float* out = (float*)d_out;

    const int Btot = in_sizes[0] / (NSTREAMS * DIM);   // 65536
    const int grid = Btot / (BM * TILES);              // 256 = 1 block/CU

    const size_t W_OFF = 256;
    const size_t need_h = 24 * sizeof(float);
    const size_t need_w = W_OFF + (size_t)DIM * DIM * sizeof(short);
    const bool has_h = ws_size >= need_h;
    const bool has_w = ws_size >= need_w;

    float* ws_h = (float*)d_ws;
    short* ws_w = (short*)((char*)d_ws + W_OFF);

    if (has_w) {
        prep_wh_kernel<<<(DIM * DIM / 4) / 256, 256, 0, stream>>>(
            Wb, ws_w, hres_l, hpre_l, hpost_l, ws_h);
        fused_kernel<true><<<grid, NTHREADS, 0, stream>>>(
            res, Wb, ws_w, ws_h, hres_l, hpre_l, hpost_l, out);
    } else if (has_h) {
        prep_h_kernel<<<1, 64, 0, stream>>>(hres_l, hpre_l, hpost_l, ws_h);
        fused_kernel<false><<<grid, NTHREADS, 0, stream>>>(
            res, Wb, nullptr, ws_h, hres_l, hpre_l, hpost_l, out);
    } else {
        fused_kernel<false><<<grid, NTHREADS, 0, stream>>>(
            res, Wb, nullptr, nullptr, hres_l, hpre_l, hpost_l, out);
    }
}

// Round 7
// 119.901 us; speedup vs baseline: 1.1315x; 1.1315x over previous
//
#include <hip/hip_runtime.h>

#define NSTREAMS 4
#define DIM 256
#define BM 16
#define NTHREADS 1024
#define TILES 16

typedef __attribute__((ext_vector_type(8))) short short8;
typedef __attribute__((ext_vector_type(4))) float f32x4;

// f32x4 -> packed bf16x4 via HW v_cvt_pk_bf16_f32 (RNE)
static __device__ __forceinline__ int2 f2bf4(float4 v) {
    unsigned int lo, hi;
    asm("v_cvt_pk_bf16_f32 %0, %1, %2" : "=v"(lo) : "v"(v.x), "v"(v.y));
    asm("v_cvt_pk_bf16_f32 %0, %1, %2" : "=v"(hi) : "v"(v.z), "v"(v.w));
    int2 r; r.x = (int)lo; r.y = (int)hi;
    return r;
}

// Block-uniform float -> SGPR (all lanes hold the same value).
static __device__ __forceinline__ float rfl(float x) {
    int i = __builtin_amdgcn_readfirstlane(__builtin_bit_cast(int, x));
    return __builtin_bit_cast(float, i);
}

// Block barrier that drains LDS ops only — does NOT drain vmcnt, so global
// loads issued before it stay in flight across the barrier (T4 discipline).
static __device__ __forceinline__ void barrier_lgkm() {
    asm volatile("s_waitcnt lgkmcnt(0)\n\ts_barrier" ::: "memory");
}

__global__ __launch_bounds__(NTHREADS, 1) void fused_kernel(
    const float* __restrict__ res,
    const float* __restrict__ Wb,
    const float* __restrict__ hres_l,
    const float* __restrict__ hpre_l,
    const float* __restrict__ hpost_l,
    float* __restrict__ out)
{
    // Single-launch design:
    //  - W lives in REGISTERS (8 short8 = 32 VGPR/lane), loaded once: the GEMM
    //    reads only bi from LDS (8 ds_read + 8 MFMA per lane per tile).
    //  - Sinkhorn computed wave-parallel (shfl butterflies) redundantly by
    //    every wave: no prep kernels, no h LDS, no extra barrier.
    //  - Loop body = R6's verified swapped-operand structure: acc holds
    //    C[batch=lr][d0..d0+3] directly; bi double-buffered; 1 barrier/tile.
    __shared__ __align__(16) short bi_lds[2][BM][DIM + 8];   // 2 x 8.25 KB

    const int t  = threadIdx.x;
    const int w  = t >> 6;    // wave id 0..15: owns d in [16w, 16w+16)
    const int l  = t & 63;
    const int lr = l & 15;    // batch row owned; also W-row lane index
    const int lk = l >> 4;    // k-block 0..3; d-subblock in the accumulator

    const long tile0 = (long)blockIdx.x * TILES;
    const long tstride = (long)BM * (NSTREAMS * DIM);
    const int d0 = w * 16 + lk * 4;
    const int dcol = w * 16 + lr;
    const float* rbase = res + (tile0 * BM + lr) * (NSTREAMS * DIM) + d0;

    // ---- issue tile-0 res loads FIRST (longest latency)
    float4 A0, A1, A2, A3;
    A0 = *reinterpret_cast<const float4*>(rbase + 0 * DIM);
    A1 = *reinterpret_cast<const float4*>(rbase + 1 * DIM);
    A2 = *reinterpret_cast<const float4*>(rbase + 2 * DIM);
    A3 = *reinterpret_cast<const float4*>(rbase + 3 * DIM);

    // ---- issue W row loads (f32, L2/L3-resident after first touch):
    //      lane needs floats Wb[dcol][kk*32 + lk*8 .. +8] for kk=0..7
    const float4* wrow4 = reinterpret_cast<const float4*>(Wb + dcol * DIM);
    float4 wfa[8], wfb[8];
    #pragma unroll
    for (int kk = 0; kk < 8; ++kk) {
        wfa[kk] = wrow4[kk * 8 + lk * 2];
        wfb[kk] = wrow4[kk * 8 + lk * 2 + 1];
    }

    // ---- wave-parallel Sinkhorn (4x4, 10 iters, tau=0.05), every wave
    //      redundantly; lane l&15 owns z[i][j] with i=bits3:2, j=bits1:0.
    float hres[4][4];
    float hp0, hp1, hp2, hp3;
    float hq[4];
    {
        const int li = l & 15;
        float z = hres_l[li] * 20.0f;          // 1/tau = 20
        float uu = 0.f, vv = 0.f;
        const float logm = -logf(4.0f);
        #pragma unroll 1
        for (int it = 0; it < 10; ++it) {
            // u-update: LSE over j (lane bits 0,1)
            float tj = z + vv;
            float m = fmaxf(tj, __shfl_xor(tj, 1));
            m = fmaxf(m, __shfl_xor(m, 2));
            float e = expf(tj - m);
            float ss = e + __shfl_xor(e, 1);
            ss += __shfl_xor(ss, 2);
            uu = logm - (m + logf(ss));
            // v-update: LSE over i (lane bits 2,3)
            float ti2 = z + uu;
            float m2 = fmaxf(ti2, __shfl_xor(ti2, 4));
            m2 = fmaxf(m2, __shfl_xor(m2, 8));
            float e2 = expf(ti2 - m2);
            float s2 = e2 + __shfl_xor(e2, 4);
            s2 += __shfl_xor(s2, 8);
            vv = logm - (m2 + logf(s2));
        }
        float hval = expf(z + uu + vv) * 4.0f;
        #pragma unroll
        for (int s = 0; s < 4; ++s)
            #pragma unroll
            for (int tt = 0; tt < 4; ++tt)
                hres[s][tt] = rfl(__shfl(hval, s * 4 + tt));
        // softmaxes (scalar per lane, block-uniform -> SGPR)
        float p0 = hpre_l[0], p1 = hpre_l[1], p2 = hpre_l[2], p3 = hpre_l[3];
        float pm = fmaxf(fmaxf(p0, p1), fmaxf(p2, p3));
        float e0 = expf(p0 - pm), e1 = expf(p1 - pm), e2 = expf(p2 - pm), e3 = expf(p3 - pm);
        float es = e0 + e1 + e2 + e3;
        hp0 = rfl(e0 / es); hp1 = rfl(e1 / es); hp2 = rfl(e2 / es); hp3 = rfl(e3 / es);
        float q0 = hpost_l[0], q1 = hpost_l[1], q2 = hpost_l[2], q3 = hpost_l[3];
        float qm = fmaxf(fmaxf(q0, q1), fmaxf(q2, q3));
        float f0 = expf(q0 - qm), f1 = expf(q1 - qm), f2 = expf(q2 - qm), f3 = expf(q3 - qm);
        float fs = f0 + f1 + f2 + f3;
        hq[0] = rfl(f0 / fs); hq[1] = rfl(f1 / fs); hq[2] = rfl(f2 / fs); hq[3] = rfl(f3 / fs);
    }

    // ---- convert W f32 -> bf16 fragments (register-resident for all tiles)
    short8 wf[8];
    #pragma unroll
    for (int kk = 0; kk < 8; ++kk) {
        union { int4 i; short8 s; } u8;
        int2 lo = f2bf4(wfa[kk]);
        int2 hi = f2bf4(wfb[kk]);
        u8.i.x = lo.x; u8.i.y = lo.y; u8.i.z = hi.x; u8.i.w = hi.y;
        wf[kk] = u8.s;
    }

    // ---- stage bi(0) into buf0 + opart(0) from A-set
    float4 opart[4];
    {
        float4 bi;
        bi.x = hp0 * A0.x + hp1 * A1.x + hp2 * A2.x + hp3 * A3.x;
        bi.y = hp0 * A0.y + hp1 * A1.y + hp2 * A2.y + hp3 * A3.y;
        bi.z = hp0 * A0.z + hp1 * A1.z + hp2 * A2.z + hp3 * A3.z;
        bi.w = hp0 * A0.w + hp1 * A1.w + hp2 * A2.w + hp3 * A3.w;
        *reinterpret_cast<int2*>(&bi_lds[0][lr][d0]) = f2bf4(bi);
        #pragma unroll
        for (int tt = 0; tt < 4; ++tt) {
            opart[tt].x = hres[0][tt] * A0.x + hres[1][tt] * A1.x + hres[2][tt] * A2.x + hres[3][tt] * A3.x;
            opart[tt].y = hres[0][tt] * A0.y + hres[1][tt] * A1.y + hres[2][tt] * A2.y + hres[3][tt] * A3.y;
            opart[tt].z = hres[0][tt] * A0.z + hres[1][tt] * A1.z + hres[2][tt] * A2.z + hres[3][tt] * A3.z;
            opart[tt].w = hres[0][tt] * A0.w + hres[1][tt] * A1.w + hres[2][tt] * A2.w + hres[3][tt] * A3.w;
        }
    }

    // ---- issue tile-1 loads into B-set (in flight across tile 0's GEMM)
    float4 B0, B1, B2, B3;
    B0 = *reinterpret_cast<const float4*>(rbase + tstride + 0 * DIM);
    B1 = *reinterpret_cast<const float4*>(rbase + tstride + 1 * DIM);
    B2 = *reinterpret_cast<const float4*>(rbase + tstride + 2 * DIM);
    B3 = *reinterpret_cast<const float4*>(rbase + tstride + 3 * DIM);

    barrier_lgkm();   // bi(0) visible

    for (int ti = 0; ti < TILES; ti += 2) {
        // ======== even half: GEMM from buf0; stage B-set -> buf1 ============
        {
            if (ti + 2 < TILES) {   // issue A-set loads for tile ti+2
                const float* rb = rbase + (ti + 2) * tstride;
                A0 = *reinterpret_cast<const float4*>(rb + 0 * DIM);
                A1 = *reinterpret_cast<const float4*>(rb + 1 * DIM);
                A2 = *reinterpret_cast<const float4*>(rb + 2 * DIM);
                A3 = *reinterpret_cast<const float4*>(rb + 3 * DIM);
            }
            __builtin_amdgcn_sched_barrier(0);
            f32x4 acc = {0.f, 0.f, 0.f, 0.f};
            #pragma unroll
            for (int kk = 0; kk < 8; ++kk) {
                short8 bfrag = *reinterpret_cast<const short8*>(&bi_lds[0][lr][kk * 32 + lk * 8]);
                acc = __builtin_amdgcn_mfma_f32_16x16x32_bf16(wf[kk], bfrag, acc, 0, 0, 0);
            }
            {   // epilogue straight from acc
                float* obase = out + (((tile0 + ti) * BM + lr) * 4) * DIM + d0;
                #pragma unroll
                for (int tt = 0; tt < 4; ++tt) {
                    float4 o;
                    o.x = opart[tt].x + hq[tt] * acc[0];
                    o.y = opart[tt].y + hq[tt] * acc[1];
                    o.z = opart[tt].z + hq[tt] * acc[2];
                    o.w = opart[tt].w + hq[tt] * acc[3];
                    *reinterpret_cast<float4*>(obase + tt * DIM) = o;
                }
            }
            {   // stage bi(ti+1) -> buf1 + opart(ti+1) from B-set
                float4 bi;
                bi.x = hp0 * B0.x + hp1 * B1.x + hp2 * B2.x + hp3 * B3.x;
                bi.y = hp0 * B0.y + hp1 * B1.y + hp2 * B2.y + hp3 * B3.y;
                bi.z = hp0 * B0.z + hp1 * B1.z + hp2 * B2.z + hp3 * B3.z;
                bi.w = hp0 * B0.w + hp1 * B1.w + hp2 * B2.w + hp3 * B3.w;
                *reinterpret_cast<int2*>(&bi_lds[1][lr][d0]) = f2bf4(bi);
                #pragma unroll
                for (int tt = 0; tt < 4; ++tt) {
                    opart[tt].x = hres[0][tt] * B0.x + hres[1][tt] * B1.x + hres[2][tt] * B2.x + hres[3][tt] * B3.x;
                    opart[tt].y = hres[0][tt] * B0.y + hres[1][tt] * B1.y + hres[2][tt] * B2.y + hres[3][tt] * B3.y;
                    opart[tt].z = hres[0][tt] * B0.z + hres[1][tt] * B1.z + hres[2][tt] * B2.z + hres[3][tt] * B3.z;
                    opart[tt].w = hres[0][tt] * B0.w + hres[1][tt] * B1.w + hres[2][tt] * B2.w + hres[3][tt] * B3.w;
                }
            }
            barrier_lgkm();   // buf1 visible; buf0 reads drained
        }
        // ======== odd half: GEMM from buf1; stage A-set -> buf0 =============
        {
            if (ti + 3 < TILES) {   // issue B-set loads for tile ti+3
                const float* rb = rbase + (ti + 3) * tstride;
                B0 = *reinterpret_cast<const float4*>(rb + 0 * DIM);
                B1 = *reinterpret_cast<const float4*>(rb + 1 * DIM);
                B2 = *reinterpret_cast<const float4*>(rb + 2 * DIM);
                B3 = *reinterpret_cast<const float4*>(rb + 3 * DIM);
            }
            __builtin_amdgcn_sched_barrier(0);
            f32x4 acc = {0.f, 0.f, 0.f, 0.f};
            #pragma unroll
            for (int kk = 0; kk < 8; ++kk) {
                short8 bfrag = *reinterpret_cast<const short8*>(&bi_lds[1][lr][kk * 32 + lk * 8]);
                acc = __builtin_amdgcn_mfma_f32_16x16x32_bf16(wf[kk], bfrag, acc, 0, 0, 0);
            }
            {
                float* obase = out + (((tile0 + ti + 1) * BM + lr) * 4) * DIM + d0;
                #pragma unroll
                for (int tt = 0; tt < 4; ++tt) {
                    float4 o;
                    o.x = opart[tt].x + hq[tt] * acc[0];
                    o.y = opart[tt].y + hq[tt] * acc[1];
                    o.z = opart[tt].z + hq[tt] * acc[2];
                    o.w = opart[tt].w + hq[tt] * acc[3];
                    *reinterpret_cast<float4*>(obase + tt * DIM) = o;
                }
            }
            if (ti + 2 < TILES) {   // stage bi(ti+2) -> buf0 + opart from A-set
                float4 bi;
                bi.x = hp0 * A0.x + hp1 * A1.x + hp2 * A2.x + hp3 * A3.x;
                bi.y = hp0 * A0.y + hp1 * A1.y + hp2 * A2.y + hp3 * A3.y;
                bi.z = hp0 * A0.z + hp1 * A1.z + hp2 * A2.z + hp3 * A3.z;
                bi.w = hp0 * A0.w + hp1 * A1.w + hp2 * A2.w + hp3 * A3.w;
                *reinterpret_cast<int2*>(&bi_lds[0][lr][d0]) = f2bf4(bi);
                #pragma unroll
                for (int tt = 0; tt < 4; ++tt) {
                    opart[tt].x = hres[0][tt] * A0.x + hres[1][tt] * A1.x + hres[2][tt] * A2.x + hres[3][tt] * A3.x;
                    opart[tt].y = hres[0][tt] * A0.y + hres[1][tt] * A1.y + hres[2][tt] * A2.y + hres[3][tt] * A3.y;
                    opart[tt].z = hres[0][tt] * A0.z + hres[1][tt] * A1.z + hres[2][tt] * A2.z + hres[3][tt] * A3.z;
                    opart[tt].w = hres[0][tt] * A0.w + hres[1][tt] * A1.w + hres[2][tt] * A2.w + hres[3][tt] * A3.w;
                }
            }
            barrier_lgkm();   // buf0 visible; buf1 reads drained
        }
    }
}

extern "C" void kernel_launch(void* const* d_in, const int* in_sizes, int n_in,
                              void* d_out, int out_size, void* d_ws, size_t ws_size,
                              hipStream_t stream) {
    const float* res     = (const float*)d_in[0];
    const float* hres_l  = (const float*)d_in[1];
    const float* hpre_l  = (const float*)d_in[2];
    const float* hpost_l = (const float*)d_in[3];
    const float* Wb      = (const float*)d_in[4];
    float* out = (float*)d_out;

    const int Btot = in_sizes[0] / (NSTREAMS * DIM);   // 65536
    const int grid = Btot / (BM * TILES);              // 256 = 1 block/CU

    fused_kernel<<<grid, NTHREADS, 0, stream>>>(
        res, Wb, hres_l, hpre_l, hpost_l, out);
}